// Round 1
// baseline (559.151 us; speedup 1.0000x reference)
//
#include <hip/hip_runtime.h>
#include <math.h>

// Problem constants (shapes fixed by setup_inputs)
namespace {
constexpr int B_ = 2;
constexpr int L_ = 1024;
constexpr int K_ = 50;        // topk = min(L, params=50)
constexpr int HID_ = 768;
constexpr int PE_ = 384;
constexpr int HALF_ = 192;
constexpr int TROWS_ = 1024;  // INIT (sinusoidal table rows)

// d_out layout (float elements, outputs concatenated in return order)
constexpr long long OUT0 = 0;                                   // layout_emb [B,L,HID]
constexpr long long OUT1 = OUT0 + (long long)B_ * L_ * HID_;    // p [B,L,K,HID]
constexpr long long OUT2 = OUT1 + (long long)B_ * L_ * K_ * HID_; // topk_index [B,L,K]
constexpr long long OUT3 = OUT2 + (long long)B_ * L_ * K_;      // local_mask [B,L,L]

// workspace layout (float elements)
constexpr long long WS_SIN = 0;                                 // sin_tab [1024,384]
constexpr long long WS_T   = WS_SIN + (long long)TROWS_ * PE_;  // T tables 4x[1024,768]
constexpr long long WS_TI  = WS_T + 4LL * TROWS_ * HID_;        // topk indices (int) [B*L*K]
}

// ---------------------------------------------------------------------------
// Sinusoidal table: tab[r, j] = sin(r*freq_j), tab[r, 192+j] = cos(r*freq_j),
// row 0 zeroed (padding_idx). freq_j = exp(j * -ln(10000)/191), fp32 like numpy.
// ---------------------------------------------------------------------------
__global__ __launch_bounds__(192) void k_sin_tab(float* __restrict__ tab) {
    const int r = blockIdx.x;
    const int j = threadIdx.x;
    const float c = -0.04822168780092243f;  // -ln(10000)/191
    float fr = expf((float)j * c);
    float ang = (float)r * fr;
    float s, co;
    if (r == 0) { s = 0.f; co = 0.f; } else { s = sinf(ang); co = cosf(ang); }
    tab[r * PE_ + j] = s;
    tab[r * PE_ + HALF_ + j] = co;
}

// ---------------------------------------------------------------------------
// Build combined tables T_t[r,o] = sum_j U_t[o,j] * sin_tab[r,j]
//   t=0: U = W_tl[:, :384] + W_bl[:, :384]   (multiplies ex1; +bias fold)
//   t=1: U = W_tr[:, :384] + W_br[:, :384]   (ex2)
//   t=2: U = W_tl[:, 384:] + W_tr[:, 384:]   (ey1)
//   t=3: U = W_bl[:, 384:] + W_br[:, 384:]   (ey2)
// Tiled fp32 GEMM: BM=64(r) x BN=64(o) x BK=32, 256 thr, 4x4 per thread.
// ---------------------------------------------------------------------------
__global__ __launch_bounds__(256) void k_build_T(
    const float* __restrict__ sinT,
    const float* __restrict__ Wtl, const float* __restrict__ Wtr,
    const float* __restrict__ Wbl, const float* __restrict__ Wbr,
    const float* __restrict__ btl, const float* __restrict__ btr,
    const float* __restrict__ bbl, const float* __restrict__ bbr,
    float* __restrict__ Tout)
{
    const int t = blockIdx.z;
    const float* Wa; const float* Wb; int coff;
    if (t == 0)      { Wa = Wtl; Wb = Wbl; coff = 0; }
    else if (t == 1) { Wa = Wtr; Wb = Wbr; coff = 0; }
    else if (t == 2) { Wa = Wtl; Wb = Wtr; coff = PE_; }
    else             { Wa = Wbl; Wb = Wbr; coff = PE_; }

    __shared__ float As[32][65];  // [k][r], padded
    __shared__ float Bs[32][65];  // [k][o], padded
    const int tid = threadIdx.x;
    const int r0 = blockIdx.x * 64;
    const int o0 = blockIdx.y * 64;
    const int ty = tid >> 4, tx = tid & 15;
    float acc[4][4] = {{0.f, 0.f, 0.f, 0.f}, {0.f, 0.f, 0.f, 0.f},
                       {0.f, 0.f, 0.f, 0.f}, {0.f, 0.f, 0.f, 0.f}};

    for (int k0 = 0; k0 < PE_; k0 += 32) {
        #pragma unroll
        for (int s = 0; s < 8; ++s) {
            int l = s * 256 + tid;
            int rr = l >> 5, jj = l & 31;
            As[jj][rr] = sinT[(r0 + rr) * PE_ + k0 + jj];
            Bs[jj][rr] = Wa[(o0 + rr) * (2 * PE_) + coff + k0 + jj]
                       + Wb[(o0 + rr) * (2 * PE_) + coff + k0 + jj];
        }
        __syncthreads();
        #pragma unroll
        for (int kk = 0; kk < 32; ++kk) {
            float a[4], b[4];
            #pragma unroll
            for (int m = 0; m < 4; ++m) a[m] = As[kk][ty * 4 + m];
            #pragma unroll
            for (int n = 0; n < 4; ++n) b[n] = Bs[kk][tx * 4 + n];
            #pragma unroll
            for (int m = 0; m < 4; ++m)
                #pragma unroll
                for (int n = 0; n < 4; ++n)
                    acc[m][n] = fmaf(a[m], b[n], acc[m][n]);
        }
        __syncthreads();
    }

    #pragma unroll
    for (int m = 0; m < 4; ++m) {
        int r = r0 + ty * 4 + m;
        #pragma unroll
        for (int n = 0; n < 4; ++n) {
            int o = o0 + tx * 4 + n;
            float v = acc[m][n];
            if (t == 0) v += btl[o] + btr[o] + bbl[o] + bbr[o];  // bias fold
            Tout[(long long)t * TROWS_ * HID_ + (long long)r * HID_ + o] = v;
        }
    }
}

// ---------------------------------------------------------------------------
// layout_emb: gather 6x128 table rows, LayerNorm(768), write.
// One block (256 thr) per token; 3 elements/thread.
// ---------------------------------------------------------------------------
__device__ __forceinline__ float block_sum_256(float x, float* red) {
    #pragma unroll
    for (int off = 32; off > 0; off >>= 1) x += __shfl_xor(x, off, 64);
    const int wave = threadIdx.x >> 6;
    if ((threadIdx.x & 63) == 0) red[wave] = x;
    __syncthreads();
    float t = red[0] + red[1] + red[2] + red[3];
    __syncthreads();
    return t;
}

__global__ __launch_bounds__(256) void k_layout_emb(
    const int4* __restrict__ bbox, const float* __restrict__ xt,
    const float* __restrict__ yt, const float* __restrict__ ht,
    const float* __restrict__ wt, const float* __restrict__ g,
    const float* __restrict__ bb, float* __restrict__ out)
{
    __shared__ float red[4];
    const int tok = blockIdx.x;           // b*L + l
    const int4 q = bbox[tok];
    const int tid = threadIdx.x;
    float v[3];
    #pragma unroll
    for (int s = 0; s < 3; ++s) {
        int e = tid + s * 256;
        int off = e & 127;
        int seg = e >> 7;
        float val;
        if (seg == 0)      val = xt[q.x * 128 + off];
        else if (seg == 1) val = yt[q.y * 128 + off];
        else if (seg == 2) val = xt[q.z * 128 + off];
        else if (seg == 3) val = yt[q.w * 128 + off];
        else if (seg == 4) val = ht[(q.w - q.y) * 128 + off];
        else               val = wt[(q.z - q.x) * 128 + off];
        v[s] = val;
    }
    float mu = block_sum_256(v[0] + v[1] + v[2], red) * (1.0f / 768.0f);
    float sq = 0.f;
    #pragma unroll
    for (int s = 0; s < 3; ++s) { float d = v[s] - mu; sq = fmaf(d, d, sq); }
    float var = block_sum_256(sq, red) * (1.0f / 768.0f);
    float inv = 1.0f / sqrtf(var + 1e-12f);
    float* orow = out + (long long)tok * HID_;
    #pragma unroll
    for (int s = 0; s < 3; ++s) {
        int e = tid + s * 256;
        orow[e] = (v[s] - mu) * inv * g[e] + bb[e];
    }
}

// ---------------------------------------------------------------------------
// top-k: one block per (b,i). Distances exact in fp32 (multiples of 0.25),
// stable tie-break via packed u64 key = (dist_bits << 32) | j, 50 argmin rounds.
// Writes topk (float to d_out, int to ws) and scatters local_mask ones.
// ---------------------------------------------------------------------------
__global__ __launch_bounds__(256) void k_topk(
    const int4* __restrict__ bbox, const int* __restrict__ am,
    float* __restrict__ topk_f, int* __restrict__ topk_i,
    float* __restrict__ mask)
{
    __shared__ float xs[L_], ys[L_];
    __shared__ unsigned long long wmin[4];
    const int bx = blockIdx.x;
    const int b = bx >> 10;
    const int i = bx & 1023;
    const int tid = threadIdx.x;
    for (int j = tid; j < L_; j += 256) {
        int4 q = bbox[b * L_ + j];
        float x1, y1, x2, y2;
        if (am[b * L_ + j] == 0) { x1 = y1 = x2 = y2 = 1e8f; }
        else { x1 = (float)q.x; y1 = (float)q.y; x2 = (float)q.z; y2 = (float)q.w; }
        xs[j] = (x1 + x2) * 0.5f;
        ys[j] = (y1 + y2) * 0.5f;
    }
    __syncthreads();
    const float xq = xs[i], yq = ys[i];
    unsigned long long key[4];
    #pragma unroll
    for (int s = 0; s < 4; ++s) {
        int j = tid + s * 256;
        float dx = xq - xs[j], dy = yq - ys[j];
        float d = dx * dx + dy * dy;
        key[s] = ((unsigned long long)__float_as_uint(d) << 32) | (unsigned int)j;
    }
    const int lane = tid & 63, wave = tid >> 6;
    const long long obase = (long long)(b * L_ + i) * K_;
    float* mrow = mask + (long long)(b * L_ + i) * L_;
    for (int r = 0; r < K_; ++r) {
        unsigned long long m = key[0] < key[1] ? key[0] : key[1];
        unsigned long long m2 = key[2] < key[3] ? key[2] : key[3];
        if (m2 < m) m = m2;
        #pragma unroll
        for (int off = 1; off < 64; off <<= 1) {
            unsigned long long o = __shfl_xor(m, off, 64);
            if (o < m) m = o;
        }
        if (lane == 0) wmin[wave] = m;
        __syncthreads();
        unsigned long long mm = wmin[0] < wmin[1] ? wmin[0] : wmin[1];
        unsigned long long mb = wmin[2] < wmin[3] ? wmin[2] : wmin[3];
        if (mb < mm) mm = mb;
        if (tid == 0) {
            int w = (int)(mm & 0xffffffffu);
            topk_f[obase + r] = (float)w;
            topk_i[obase + r] = w;
            mrow[w] = 1.0f;
        }
        #pragma unroll
        for (int s = 0; s < 4; ++s) if (key[s] == mm) key[s] = ~0ULL;  // remove winner
        __syncthreads();
    }
}

// ---------------------------------------------------------------------------
// p assembly: p[row,:] = T1[r1] + T2[r2] + T3[r3] + T4[r4]  (bias in T1)
// One wave per row, float4 loads. T tables (12.6 MB) are L2/L3 resident.
// ---------------------------------------------------------------------------
__device__ __forceinline__ int wrapc(int d) {
    d = d < -1000 ? -1000 : (d > 1000 ? 1000 : d);  // clip [1-MAX2D, MAX2D-1]
    return (d + 1024) & 1023;                        // mod INIT (d >= -1000)
}

__global__ __launch_bounds__(256) void k_passemble(
    const int4* __restrict__ bbox, const int* __restrict__ topk_i,
    const float4* __restrict__ T, float* __restrict__ p)
{
    const int row = blockIdx.x * 4 + (threadIdx.x >> 6);  // (b*L+i)*K + k
    const int lane = threadIdx.x & 63;
    const int b = row / (L_ * K_);
    const int rem = row - b * (L_ * K_);
    const int i = rem / K_;
    const int j = topk_i[row];
    const int4 bi = bbox[b * L_ + i];
    const int4 bj = bbox[b * L_ + j];
    const float4* T1 = T + (long long)wrapc(bi.x - bj.x) * 192;            // ex1
    const float4* T2 = T + 196608 + (long long)wrapc(bi.z - bj.z) * 192;   // ex2
    const float4* T3 = T + 2 * 196608 + (long long)wrapc(bi.y - bj.y) * 192; // ey1
    const float4* T4 = T + 3 * 196608 + (long long)wrapc(bi.w - bj.w) * 192; // ey2
    float4* prow = (float4*)p + (long long)row * 192;
    #pragma unroll
    for (int u = 0; u < 3; ++u) {
        int f = lane + u * 64;
        float4 a = T1[f], c = T2[f], d = T3[f], e = T4[f];
        float4 o;
        o.x = a.x + c.x + d.x + e.x;
        o.y = a.y + c.y + d.y + e.y;
        o.z = a.z + c.z + d.z + e.z;
        o.w = a.w + c.w + d.w + e.w;
        prow[f] = o;
    }
}

// ---------------------------------------------------------------------------
extern "C" void kernel_launch(void* const* d_in, const int* in_sizes, int n_in,
                              void* d_out, int out_size, void* d_ws, size_t ws_size,
                              hipStream_t stream)
{
    const int4* bbox = (const int4*)d_in[0];
    const int* am    = (const int*)d_in[1];
    const float* xt  = (const float*)d_in[2];
    const float* yt  = (const float*)d_in[3];
    const float* ht  = (const float*)d_in[4];
    const float* wt  = (const float*)d_in[5];
    const float* Wtl = (const float*)d_in[6];
    const float* btl = (const float*)d_in[7];
    const float* Wtr = (const float*)d_in[8];
    const float* btr = (const float*)d_in[9];
    const float* Wbl = (const float*)d_in[10];
    const float* bbl = (const float*)d_in[11];
    const float* Wbr = (const float*)d_in[12];
    const float* bbr = (const float*)d_in[13];
    const float* lng = (const float*)d_in[14];
    const float* lnb = (const float*)d_in[15];
    // d_in[16] = params (50) — baked into K_

    float* out = (float*)d_out;
    float* ws = (float*)d_ws;
    float* sinT = ws + WS_SIN;
    float* T = ws + WS_T;
    int* topk_i = (int*)(ws + WS_TI);

    // local_mask region must start at zero (buffer is poisoned before each run)
    hipMemsetAsync(out + OUT3, 0, (size_t)B_ * L_ * L_ * sizeof(float), stream);

    k_sin_tab<<<dim3(TROWS_), dim3(HALF_), 0, stream>>>(sinT);
    k_build_T<<<dim3(16, 12, 4), dim3(256), 0, stream>>>(
        sinT, Wtl, Wtr, Wbl, Wbr, btl, btr, bbl, bbr, T);
    k_layout_emb<<<dim3(B_ * L_), dim3(256), 0, stream>>>(
        bbox, xt, yt, ht, wt, lng, lnb, out + OUT0);
    k_topk<<<dim3(B_ * L_), dim3(256), 0, stream>>>(
        bbox, am, out + OUT2, topk_i, out + OUT3);
    k_passemble<<<dim3(B_ * L_ * K_ / 4), dim3(256), 0, stream>>>(
        bbox, topk_i, (const float4*)T, out + OUT1);
}

// Round 3
// 521.972 us; speedup vs baseline: 1.0712x; 1.0712x over previous
//
#include <hip/hip_runtime.h>
#include <math.h>

// Problem constants (shapes fixed by setup_inputs)
namespace {
constexpr int B_ = 2;
constexpr int L_ = 1024;
constexpr int K_ = 50;        // topk = min(L, params=50)
constexpr int HID_ = 768;
constexpr int PE_ = 384;
constexpr int HALF_ = 192;
constexpr int TROWS_ = 1024;  // INIT (sinusoidal table rows)

typedef float f32x4 __attribute__((ext_vector_type(4)));  // nontemporal-friendly

// d_out layout (float elements, outputs concatenated in return order)
constexpr long long OUT0 = 0;                                   // layout_emb [B,L,HID]
constexpr long long OUT1 = OUT0 + (long long)B_ * L_ * HID_;    // p [B,L,K,HID]
constexpr long long OUT2 = OUT1 + (long long)B_ * L_ * K_ * HID_; // topk_index [B,L,K]
constexpr long long OUT3 = OUT2 + (long long)B_ * L_ * K_;      // local_mask [B,L,L]

// workspace layout (float elements)
constexpr long long WS_SIN = 0;                                 // sin_tab [1024,384]
constexpr long long WS_T   = WS_SIN + (long long)TROWS_ * PE_;  // T tables 4x[1024,768]
constexpr long long WS_TI  = WS_T + 4LL * TROWS_ * HID_;        // topk indices (int) [B*L*K]
}

// ---------------------------------------------------------------------------
// Sinusoidal table: tab[r, j] = sin(r*freq_j), tab[r, 192+j] = cos(r*freq_j),
// row 0 zeroed (padding_idx). freq_j = exp(j * -ln(10000)/191), fp32 like numpy.
// ---------------------------------------------------------------------------
__global__ __launch_bounds__(192) void k_sin_tab(float* __restrict__ tab) {
    const int r = blockIdx.x;
    const int j = threadIdx.x;
    const float c = -0.04822168780092243f;  // -ln(10000)/191
    float fr = expf((float)j * c);
    float ang = (float)r * fr;
    float s, co;
    if (r == 0) { s = 0.f; co = 0.f; } else { s = sinf(ang); co = cosf(ang); }
    tab[r * PE_ + j] = s;
    tab[r * PE_ + HALF_ + j] = co;
}

// ---------------------------------------------------------------------------
// Build combined tables T_t[r,o] = sum_j U_t[o,j] * sin_tab[r,j]
//   t=0: U = W_tl[:, :384] + W_bl[:, :384]   (multiplies ex1; +bias fold)
//   t=1: U = W_tr[:, :384] + W_br[:, :384]   (ex2)
//   t=2: U = W_tl[:, 384:] + W_tr[:, 384:]   (ey1)
//   t=3: U = W_bl[:, 384:] + W_br[:, 384:]   (ey2)
// Tiled fp32 GEMM: BM=64(r) x BN=64(o) x BK=32, 256 thr, 4x4 per thread.
// ---------------------------------------------------------------------------
__global__ __launch_bounds__(256) void k_build_T(
    const float* __restrict__ sinT,
    const float* __restrict__ Wtl, const float* __restrict__ Wtr,
    const float* __restrict__ Wbl, const float* __restrict__ Wbr,
    const float* __restrict__ btl, const float* __restrict__ btr,
    const float* __restrict__ bbl, const float* __restrict__ bbr,
    float* __restrict__ Tout)
{
    const int t = blockIdx.z;
    const float* Wa; const float* Wb; int coff;
    if (t == 0)      { Wa = Wtl; Wb = Wbl; coff = 0; }
    else if (t == 1) { Wa = Wtr; Wb = Wbr; coff = 0; }
    else if (t == 2) { Wa = Wtl; Wb = Wtr; coff = PE_; }
    else             { Wa = Wbl; Wb = Wbr; coff = PE_; }

    __shared__ float As[32][65];  // [k][r], padded
    __shared__ float Bs[32][65];  // [k][o], padded
    const int tid = threadIdx.x;
    const int r0 = blockIdx.x * 64;
    const int o0 = blockIdx.y * 64;
    const int ty = tid >> 4, tx = tid & 15;
    float acc[4][4] = {{0.f, 0.f, 0.f, 0.f}, {0.f, 0.f, 0.f, 0.f},
                       {0.f, 0.f, 0.f, 0.f}, {0.f, 0.f, 0.f, 0.f}};

    for (int k0 = 0; k0 < PE_; k0 += 32) {
        #pragma unroll
        for (int s = 0; s < 8; ++s) {
            int l = s * 256 + tid;
            int rr = l >> 5, jj = l & 31;
            As[jj][rr] = sinT[(r0 + rr) * PE_ + k0 + jj];
            Bs[jj][rr] = Wa[(o0 + rr) * (2 * PE_) + coff + k0 + jj]
                       + Wb[(o0 + rr) * (2 * PE_) + coff + k0 + jj];
        }
        __syncthreads();
        #pragma unroll
        for (int kk = 0; kk < 32; ++kk) {
            float a[4], b[4];
            #pragma unroll
            for (int m = 0; m < 4; ++m) a[m] = As[kk][ty * 4 + m];
            #pragma unroll
            for (int n = 0; n < 4; ++n) b[n] = Bs[kk][tx * 4 + n];
            #pragma unroll
            for (int m = 0; m < 4; ++m)
                #pragma unroll
                for (int n = 0; n < 4; ++n)
                    acc[m][n] = fmaf(a[m], b[n], acc[m][n]);
        }
        __syncthreads();
    }

    #pragma unroll
    for (int m = 0; m < 4; ++m) {
        int r = r0 + ty * 4 + m;
        #pragma unroll
        for (int n = 0; n < 4; ++n) {
            int o = o0 + tx * 4 + n;
            float v = acc[m][n];
            if (t == 0) v += btl[o] + btr[o] + bbl[o] + bbr[o];  // bias fold
            Tout[(long long)t * TROWS_ * HID_ + (long long)r * HID_ + o] = v;
        }
    }
}

// ---------------------------------------------------------------------------
// layout_emb: gather 6x128 table rows, LayerNorm(768), write.
// One block (256 thr) per token; 3 elements/thread.
// ---------------------------------------------------------------------------
__device__ __forceinline__ float block_sum_256(float x, float* red) {
    #pragma unroll
    for (int off = 32; off > 0; off >>= 1) x += __shfl_xor(x, off, 64);
    const int wave = threadIdx.x >> 6;
    if ((threadIdx.x & 63) == 0) red[wave] = x;
    __syncthreads();
    float t = red[0] + red[1] + red[2] + red[3];
    __syncthreads();
    return t;
}

__global__ __launch_bounds__(256) void k_layout_emb(
    const int4* __restrict__ bbox, const float* __restrict__ xt,
    const float* __restrict__ yt, const float* __restrict__ ht,
    const float* __restrict__ wt, const float* __restrict__ g,
    const float* __restrict__ bb, float* __restrict__ out)
{
    __shared__ float red[4];
    const int tok = blockIdx.x;           // b*L + l
    const int4 q = bbox[tok];
    const int tid = threadIdx.x;
    float v[3];
    #pragma unroll
    for (int s = 0; s < 3; ++s) {
        int e = tid + s * 256;
        int off = e & 127;
        int seg = e >> 7;
        float val;
        if (seg == 0)      val = xt[q.x * 128 + off];
        else if (seg == 1) val = yt[q.y * 128 + off];
        else if (seg == 2) val = xt[q.z * 128 + off];
        else if (seg == 3) val = yt[q.w * 128 + off];
        else if (seg == 4) val = ht[(q.w - q.y) * 128 + off];
        else               val = wt[(q.z - q.x) * 128 + off];
        v[s] = val;
    }
    float mu = block_sum_256(v[0] + v[1] + v[2], red) * (1.0f / 768.0f);
    float sq = 0.f;
    #pragma unroll
    for (int s = 0; s < 3; ++s) { float d = v[s] - mu; sq = fmaf(d, d, sq); }
    float var = block_sum_256(sq, red) * (1.0f / 768.0f);
    float inv = 1.0f / sqrtf(var + 1e-12f);
    float* orow = out + (long long)tok * HID_;
    #pragma unroll
    for (int s = 0; s < 3; ++s) {
        int e = tid + s * 256;
        __builtin_nontemporal_store((v[s] - mu) * inv * g[e] + bb[e], orow + e);
    }
}

// ---------------------------------------------------------------------------
// top-k: one block per (b,i). Distances exact in fp32 (multiples of 0.25),
// stable tie-break via packed u64 key = (dist_bits << 32) | j, 50 argmin rounds.
// Builds the local_mask row in LDS and writes it once (no global memset pass).
// ---------------------------------------------------------------------------
__global__ __launch_bounds__(256) void k_topk(
    const int4* __restrict__ bbox, const int* __restrict__ am,
    float* __restrict__ topk_f, int* __restrict__ topk_i,
    float* __restrict__ mask)
{
    __shared__ float xs[L_], ys[L_];
    __shared__ float mrow_s[L_];
    __shared__ unsigned long long wmin[4];
    const int bx = blockIdx.x;
    const int b = bx >> 10;
    const int i = bx & 1023;
    const int tid = threadIdx.x;
    for (int j = tid; j < L_; j += 256) {
        int4 q = bbox[b * L_ + j];
        float x1, y1, x2, y2;
        if (am[b * L_ + j] == 0) { x1 = y1 = x2 = y2 = 1e8f; }
        else { x1 = (float)q.x; y1 = (float)q.y; x2 = (float)q.z; y2 = (float)q.w; }
        xs[j] = (x1 + x2) * 0.5f;
        ys[j] = (y1 + y2) * 0.5f;
        mrow_s[j] = 0.f;
    }
    __syncthreads();
    const float xq = xs[i], yq = ys[i];
    unsigned long long key[4];
    #pragma unroll
    for (int s = 0; s < 4; ++s) {
        int j = tid + s * 256;
        float dx = xq - xs[j], dy = yq - ys[j];
        float d = dx * dx + dy * dy;
        key[s] = ((unsigned long long)__float_as_uint(d) << 32) | (unsigned int)j;
    }
    const int lane = tid & 63, wave = tid >> 6;
    const long long obase = (long long)(b * L_ + i) * K_;
    for (int r = 0; r < K_; ++r) {
        unsigned long long m = key[0] < key[1] ? key[0] : key[1];
        unsigned long long m2 = key[2] < key[3] ? key[2] : key[3];
        if (m2 < m) m = m2;
        #pragma unroll
        for (int off = 1; off < 64; off <<= 1) {
            unsigned long long o = __shfl_xor(m, off, 64);
            if (o < m) m = o;
        }
        if (lane == 0) wmin[wave] = m;
        __syncthreads();
        unsigned long long mm = wmin[0] < wmin[1] ? wmin[0] : wmin[1];
        unsigned long long mb = wmin[2] < wmin[3] ? wmin[2] : wmin[3];
        if (mb < mm) mm = mb;
        if (tid == 0) {
            int w = (int)(mm & 0xffffffffu);
            topk_f[obase + r] = (float)w;
            topk_i[obase + r] = w;
            mrow_s[w] = 1.0f;
        }
        #pragma unroll
        for (int s = 0; s < 4; ++s) if (key[s] == mm) key[s] = ~0ULL;  // remove winner
        __syncthreads();
    }
    // write the mask row (streamed, no L2 pollution)
    f32x4* mrow = (f32x4*)(mask + (long long)(b * L_ + i) * L_);
    const f32x4* src = (const f32x4*)mrow_s;
    __builtin_nontemporal_store(src[tid], mrow + tid);
}

// ---------------------------------------------------------------------------
// p assembly: p[row,:] = T1[r1] + T2[r2] + T3[r3] + T4[r4]  (bias in T1)
// One wave per row, float4 loads. Non-temporal stores keep the 315 MB write
// stream out of L2 so the hot T rows (KNN deltas cluster near 0) stay cached.
// ---------------------------------------------------------------------------
__device__ __forceinline__ int wrapc(int d) {
    d = d < -1000 ? -1000 : (d > 1000 ? 1000 : d);  // clip [1-MAX2D, MAX2D-1]
    return (d + 1024) & 1023;                        // mod INIT (d >= -1000)
}

__global__ __launch_bounds__(256) void k_passemble(
    const int4* __restrict__ bbox, const int* __restrict__ topk_i,
    const f32x4* __restrict__ T, float* __restrict__ p)
{
    const int row = blockIdx.x * 4 + (threadIdx.x >> 6);  // (b*L+i)*K + k
    const int lane = threadIdx.x & 63;
    const int b = row / (L_ * K_);
    const int rem = row - b * (L_ * K_);
    const int i = rem / K_;
    const int j = topk_i[row];
    const int4 bi = bbox[b * L_ + i];
    const int4 bj = bbox[b * L_ + j];
    const f32x4* T1 = T + (long long)wrapc(bi.x - bj.x) * 192;              // ex1
    const f32x4* T2 = T + 196608 + (long long)wrapc(bi.z - bj.z) * 192;     // ex2
    const f32x4* T3 = T + 2 * 196608 + (long long)wrapc(bi.y - bj.y) * 192; // ey1
    const f32x4* T4 = T + 3 * 196608 + (long long)wrapc(bi.w - bj.w) * 192; // ey2
    f32x4* prow = (f32x4*)p + (long long)row * 192;
    #pragma unroll
    for (int u = 0; u < 3; ++u) {
        int f = lane + u * 64;
        f32x4 o = T1[f] + T2[f] + T3[f] + T4[f];
        __builtin_nontemporal_store(o, prow + f);
    }
}

// ---------------------------------------------------------------------------
extern "C" void kernel_launch(void* const* d_in, const int* in_sizes, int n_in,
                              void* d_out, int out_size, void* d_ws, size_t ws_size,
                              hipStream_t stream)
{
    const int4* bbox = (const int4*)d_in[0];
    const int* am    = (const int*)d_in[1];
    const float* xt  = (const float*)d_in[2];
    const float* yt  = (const float*)d_in[3];
    const float* ht  = (const float*)d_in[4];
    const float* wt  = (const float*)d_in[5];
    const float* Wtl = (const float*)d_in[6];
    const float* btl = (const float*)d_in[7];
    const float* Wtr = (const float*)d_in[8];
    const float* btr = (const float*)d_in[9];
    const float* Wbl = (const float*)d_in[10];
    const float* bbl = (const float*)d_in[11];
    const float* Wbr = (const float*)d_in[12];
    const float* bbr = (const float*)d_in[13];
    const float* lng = (const float*)d_in[14];
    const float* lnb = (const float*)d_in[15];
    // d_in[16] = params (50) — baked into K_

    float* out = (float*)d_out;
    float* ws = (float*)d_ws;
    float* sinT = ws + WS_SIN;
    float* T = ws + WS_T;
    int* topk_i = (int*)(ws + WS_TI);

    k_sin_tab<<<dim3(TROWS_), dim3(HALF_), 0, stream>>>(sinT);
    k_build_T<<<dim3(16, 12, 4), dim3(256), 0, stream>>>(
        sinT, Wtl, Wtr, Wbl, Wbr, btl, btr, bbl, bbr, T);
    k_layout_emb<<<dim3(B_ * L_), dim3(256), 0, stream>>>(
        bbox, xt, yt, ht, wt, lng, lnb, out + OUT0);
    k_topk<<<dim3(B_ * L_), dim3(256), 0, stream>>>(
        bbox, am, out + OUT2, topk_i, out + OUT3);
    k_passemble<<<dim3(B_ * L_ * K_ / 4), dim3(256), 0, stream>>>(
        bbox, topk_i, (const f32x4*)T, out + OUT1);
}